// Round 10
// baseline (479.421 us; speedup 1.0000x reference)
//
#include <hip/hip_runtime.h>
#include <hip/hip_bf16.h>
#include <hip/hip_cooperative_groups.h>
#include <math.h>

namespace cg = cooperative_groups;

// GCN 3-layer inference. N=100000, E=3200000, feats 128->4->2->1.
// R10: single cooperative mega-kernel, R8-proven phase internals.
//  P0: blocks<psB run partscatter (CHUNK=4096 LDS counting-sort by
//      bucket(dst>>8), device-atomic region alloc, 16-lane segment copy);
//      remaining blocks run node1 (128->4 GEMM, quad-per-node) concurrently.
//  P1: degree2 per bucket: double global read (no 36KB LDS buffer),
//      count+scan -> cnt/off/dinv, scale hs1*=dinv, out-of-place counting
//      sort pairs2 -> ssrc.
//  P2/P3/P4: gathers, 8 lanes/node over contiguous CSR, fused epilogues.
// grid.sync() between phases (device-scope fence for cross-XCD visibility).
// Edge pack: p = src | (dst&255)<<17  (src < 2^17).

#define TPB 256
#define CHUNK 4096
#define EPT (CHUNK / TPB)   // 16
#define SLAB2 9216          // per-bucket capacity (mean 8184, +11 sigma)

struct Prm {
    const float* x; const int* src; const int* dst;
    const float* W1; const float* b1; const float* W2; const float* b2;
    const float* W3; const float* b3;
    unsigned int* pairs2; int* cursor; int* ssrc;
    int* cnt; int* off; float* dinv;
    float* hs1; float* hs2; float* hs3; float* out;
    int N, E, NS, NB, psB;
};

union SH {
    struct { int hist[512]; int s[TPB]; int gstart[512]; unsigned int sorted[CHUNK]; } ps; // 21504 B
    struct { int c[TPB]; int s[TPB]; int cur[TPB]; } dg;
    float Ws[512];
};

__global__ __launch_bounds__(TPB) void k_mega(Prm p) {
    cg::grid_group grid = cg::this_grid();
    __shared__ SH sh;
    int t = threadIdx.x;

    // ================= P0: partscatter || node1 =================
    if ((int)blockIdx.x < p.psB) {
        for (int blk = blockIdx.x; blk < p.NS; blk += p.psB) {
            __syncthreads();                 // protect sh reuse across iters
            int base = blk * CHUNK;
            int n = min(CHUNK, p.E - base);
            sh.ps.hist[t] = 0; sh.ps.hist[t + 256] = 0;
            __syncthreads();
            unsigned int meta[EPT];          // d<<13 | lp (lp < 4096)
#pragma unroll
            for (int k = 0; k < EPT; ++k) {
                int li = k * TPB + t;
                if (li < n) {
                    int d = p.dst[base + li];
                    int lp = atomicAdd(&sh.ps.hist[d >> 8], 1);
                    meta[k] = ((unsigned)d << 13) | (unsigned)lp;
                } else meta[k] = 0xFFFFFFFFu;
            }
            __syncthreads();
            // exclusive scan hist[0..511]
            int run = 0;
            for (int cb = 0; cb < 512; cb += TPB) {
                int v = sh.ps.hist[cb + t];
                sh.ps.s[t] = v;
                __syncthreads();
                int x = v;
                for (int d = 1; d < TPB; d <<= 1) {
                    int y = (t >= d) ? sh.ps.s[t - d] : 0;
                    __syncthreads();
                    x += y; sh.ps.s[t] = x;
                    __syncthreads();
                }
                sh.ps.hist[cb + t] = run + (x - v);
                run += sh.ps.s[TPB - 1];
                __syncthreads();
            }
            // scatter into LDS sorted order
#pragma unroll
            for (int k = 0; k < EPT; ++k) {
                if (meta[k] != 0xFFFFFFFFu) {
                    unsigned m = meta[k];
                    int d = (int)(m >> 13);
                    int lp = (int)(m & 0x1FFFu);
                    unsigned pk = (unsigned)p.src[base + k * TPB + t] |
                                  ((unsigned)(d & 255) << 17);
                    sh.ps.sorted[sh.ps.hist[d >> 8] + lp] = pk;
                }
            }
            // per-bin global region alloc (one device atomic per non-empty bin)
            for (int b = t; b < p.NB; b += TPB) {
                int len = sh.ps.hist[b + 1] - sh.ps.hist[b];  // hist[NB]==n
                sh.ps.gstart[b] = (len > 0) ? atomicAdd(&p.cursor[b], len) : 0;
            }
            __syncthreads();
            // 16-lane group per segment: contiguous copy into bucket region
            int grp = t >> 4, ln = t & 15;
            for (int b = grp; b < p.NB; b += 16) {
                int ls = sh.ps.hist[b];
                int len = sh.ps.hist[b + 1] - ls;
                int gs = sh.ps.gstart[b];
                unsigned int* dp = p.pairs2 + (size_t)b * SLAB2;
                int lim = min(gs + len, SLAB2);     // overflow guard
                for (int k = gs + ln; k < lim; k += 16)
                    dp[k] = sh.ps.sorted[ls + (k - gs)];
            }
        }
    } else {
        // node1: hs1 = x@W1 (raw). Quad-per-node, grid-stride.
        for (int i = t; i < 512; i += TPB) sh.Ws[i] = p.W1[i];
        __syncthreads();
        int nb = gridDim.x - p.psB;
        for (int tt = ((int)blockIdx.x - p.psB) * TPB + t; tt < 4 * p.N;
             tt += nb * TPB) {
            int v = tt >> 2, q = tt & 3;
            const float4* xr = (const float4*)(p.x + (size_t)v * 128);
            float a0 = 0.f, a1 = 0.f, a2 = 0.f, a3 = 0.f;
#pragma unroll
            for (int i = 0; i < 8; ++i) {
                int c = q + i * 4;
                float4 xx = xr[c];
                const float* w = &sh.Ws[c * 16];
                a0 += xx.x * w[0] + xx.y * w[4] + xx.z * w[8]  + xx.w * w[12];
                a1 += xx.x * w[1] + xx.y * w[5] + xx.z * w[9]  + xx.w * w[13];
                a2 += xx.x * w[2] + xx.y * w[6] + xx.z * w[10] + xx.w * w[14];
                a3 += xx.x * w[3] + xx.y * w[7] + xx.z * w[11] + xx.w * w[15];
            }
            a0 += __shfl_xor(a0, 1); a0 += __shfl_xor(a0, 2);
            a1 += __shfl_xor(a1, 1); a1 += __shfl_xor(a1, 2);
            a2 += __shfl_xor(a2, 1); a2 += __shfl_xor(a2, 2);
            a3 += __shfl_xor(a3, 1); a3 += __shfl_xor(a3, 2);
            if (q == 0) ((float4*)p.hs1)[v] = make_float4(a0, a1, a2, a3);
        }
    }
    grid.sync();

    // ================= P1: degree2 (double global read) =================
    for (int b = blockIdx.x; b < p.NB; b += gridDim.x) {
        __syncthreads();
        sh.dg.c[t] = 0;
        __syncthreads();
        int base = b * SLAB2;
        int total = min(p.cursor[b], SLAB2);
        for (int i = t; i < total; i += TPB)
            atomicAdd(&sh.dg.c[(p.pairs2[base + i] >> 17) & 255], 1);
        __syncthreads();
        int cv = sh.dg.c[t];
        sh.dg.s[t] = cv;
        __syncthreads();
        int x = cv;
        for (int d = 1; d < TPB; d <<= 1) {
            int y = (t >= d) ? sh.dg.s[t - d] : 0;
            __syncthreads();
            x += y; sh.dg.s[t] = x;
            __syncthreads();
        }
        int excl = x - cv;
        int v = (b << 8) + t;
        if (v < p.N) {
            p.cnt[v] = cv;
            p.off[v] = base + excl;
            float di = rsqrtf((float)(cv + 1));
            p.dinv[v] = di;
            float4 h = ((float4*)p.hs1)[v];
            ((float4*)p.hs1)[v] = make_float4(di * h.x, di * h.y, di * h.z, di * h.w);
        }
        sh.dg.cur[t] = excl;
        __syncthreads();
        // out-of-place counting sort: pairs2 -> dst-sorted src list ssrc
        for (int i = t; i < total; i += TPB) {
            unsigned pp = p.pairs2[base + i];
            int pos = atomicAdd(&sh.dg.cur[(pp >> 17) & 255], 1);
            p.ssrc[base + pos] = (int)(pp & 0x1FFFFu);
        }
    }
    grid.sync();

    // ================= P2: gather1 (+relu+W2) =================
    for (int tt = blockIdx.x * TPB + t; tt < 8 * p.N; tt += gridDim.x * TPB) {
        int v = tt >> 3, q = tt & 7;
        int base = p.off[v], c = p.cnt[v];
        float4 acc = make_float4(0.f, 0.f, 0.f, 0.f);
        for (int i = q; i < c; i += 8) {
            int s = p.ssrc[base + i];
            float4 h = ((const float4*)p.hs1)[s];
            acc.x += h.x; acc.y += h.y; acc.z += h.z; acc.w += h.w;
        }
        acc.x += __shfl_xor(acc.x, 1); acc.x += __shfl_xor(acc.x, 2); acc.x += __shfl_xor(acc.x, 4);
        acc.y += __shfl_xor(acc.y, 1); acc.y += __shfl_xor(acc.y, 2); acc.y += __shfl_xor(acc.y, 4);
        acc.z += __shfl_xor(acc.z, 1); acc.z += __shfl_xor(acc.z, 2); acc.z += __shfl_xor(acc.z, 4);
        acc.w += __shfl_xor(acc.w, 1); acc.w += __shfl_xor(acc.w, 2); acc.w += __shfl_xor(acc.w, 4);
        if (q == 0) {
            float4 hv = ((const float4*)p.hs1)[v];
            float di = p.dinv[v];
            float o0 = fmaxf(di * (acc.x + hv.x) + p.b1[0], 0.f);
            float o1 = fmaxf(di * (acc.y + hv.y) + p.b1[1], 0.f);
            float o2 = fmaxf(di * (acc.z + hv.z) + p.b1[2], 0.f);
            float o3 = fmaxf(di * (acc.w + hv.w) + p.b1[3], 0.f);
            float h0 = o0 * p.W2[0] + o1 * p.W2[2] + o2 * p.W2[4] + o3 * p.W2[6];
            float h1 = o0 * p.W2[1] + o1 * p.W2[3] + o2 * p.W2[5] + o3 * p.W2[7];
            ((float2*)p.hs2)[v] = make_float2(di * h0, di * h1);
        }
    }
    grid.sync();

    // ================= P3: gather2 (+relu+W3) =================
    for (int tt = blockIdx.x * TPB + t; tt < 8 * p.N; tt += gridDim.x * TPB) {
        int v = tt >> 3, q = tt & 7;
        int base = p.off[v], c = p.cnt[v];
        float2 acc = make_float2(0.f, 0.f);
        for (int i = q; i < c; i += 8) {
            int s = p.ssrc[base + i];
            float2 h = ((const float2*)p.hs2)[s];
            acc.x += h.x; acc.y += h.y;
        }
        acc.x += __shfl_xor(acc.x, 1); acc.x += __shfl_xor(acc.x, 2); acc.x += __shfl_xor(acc.x, 4);
        acc.y += __shfl_xor(acc.y, 1); acc.y += __shfl_xor(acc.y, 2); acc.y += __shfl_xor(acc.y, 4);
        if (q == 0) {
            float2 hv = ((const float2*)p.hs2)[v];
            float di = p.dinv[v];
            float o0 = fmaxf(di * (acc.x + hv.x) + p.b2[0], 0.f);
            float o1 = fmaxf(di * (acc.y + hv.y) + p.b2[1], 0.f);
            float h3 = o0 * p.W3[0] + o1 * p.W3[1];
            p.hs3[v] = di * h3;
        }
    }
    grid.sync();

    // ================= P4: gather3 (+sigmoid) =================
    for (int tt = blockIdx.x * TPB + t; tt < 8 * p.N; tt += gridDim.x * TPB) {
        int v = tt >> 3, q = tt & 7;
        int base = p.off[v], c = p.cnt[v];
        float acc = 0.f;
        for (int i = q; i < c; i += 8) acc += p.hs3[p.ssrc[base + i]];
        acc += __shfl_xor(acc, 1); acc += __shfl_xor(acc, 2); acc += __shfl_xor(acc, 4);
        if (q == 0) {
            float di = p.dinv[v];
            float agg = di * (acc + p.hs3[v]) + p.b3[0];
            p.out[v] = 1.0f / (1.0f + __expf(-agg));
        }
    }
}

extern "C" void kernel_launch(void* const* d_in, const int* in_sizes, int n_in,
                              void* d_out, int out_size, void* d_ws, size_t ws_size,
                              hipStream_t stream) {
    const float* x  = (const float*)d_in[0];
    const int* ei   = (const int*)d_in[1];

    const int N = in_sizes[0] / 128;
    const int E = in_sizes[1] / 2;

    const int NS = (E + CHUNK - 1) / CHUNK;   // 782 chunks
    const int NB = (N + 255) >> 8;            // 391 buckets

    // ws carve (~33 MB)
    char* w = (char*)d_ws;
    auto carve = [&](size_t bytes) { char* q = w; w += (bytes + 15) & ~(size_t)15; return q; };
    unsigned int* pairs2 = (unsigned int*)carve((size_t)NB * SLAB2 * 4);
    int* ssrc            = (int*)carve((size_t)NB * SLAB2 * 4);
    int* cursor          = (int*)carve((size_t)NB * 4);
    int* cnt             = (int*)carve((size_t)N * 4);
    int* off             = (int*)carve((size_t)N * 4);
    float* dinv          = (float*)carve((size_t)N * 4);
    float* hs1           = (float*)carve((size_t)N * 16);
    float* hs2           = (float*)carve((size_t)N * 8);
    float* hs3           = (float*)carve((size_t)N * 4);

    int numCU = 256, maxB = 0;
    hipDeviceGetAttribute(&numCU, hipDeviceAttributeMultiprocessorCount, 0);
    hipOccupancyMaxActiveBlocksPerMultiprocessor(&maxB, k_mega, TPB, 0);
    if (maxB < 1) maxB = 1;
    int grid = numCU * maxB;
    if (grid < 8) grid = 8;

    int psB = (grid * 3) / 4;
    if (psB > NS) psB = NS;
    if (psB >= grid) psB = grid - 1;
    if (psB < 1) psB = 1;

    Prm prm;
    prm.x = x; prm.src = ei; prm.dst = ei + E;
    prm.W1 = (const float*)d_in[2]; prm.b1 = (const float*)d_in[3];
    prm.W2 = (const float*)d_in[4]; prm.b2 = (const float*)d_in[5];
    prm.W3 = (const float*)d_in[6]; prm.b3 = (const float*)d_in[7];
    prm.pairs2 = pairs2; prm.cursor = cursor; prm.ssrc = ssrc;
    prm.cnt = cnt; prm.off = off; prm.dinv = dinv;
    prm.hs1 = hs1; prm.hs2 = hs2; prm.hs3 = hs3; prm.out = (float*)d_out;
    prm.N = N; prm.E = E; prm.NS = NS; prm.NB = NB; prm.psB = psB;

    hipMemsetAsync(cursor, 0, (size_t)NB * 4, stream);
    void* args[] = { &prm };
    hipLaunchCooperativeKernel((void*)k_mega, dim3(grid), dim3(TPB), args, 0, stream);
}